// Round 7
// baseline (170.496 us; speedup 1.0000x reference)
//
#include <hip/hip_runtime.h>
#include <hip/hip_bf16.h>

#define Bn   16
#define LATn 512
#define Cn   512
#define Wn   4096
#define Fn   512

using bf16x8 = __attribute__((ext_vector_type(8))) short;
using f32x4  = __attribute__((ext_vector_type(4))) float;

__device__ __forceinline__ unsigned short f2bf(float x) {
    union { float f; unsigned int u; } v; v.f = x;
    unsigned int r = v.u + 0x7fffu + ((v.u >> 16) & 1u);
    return (unsigned short)(r >> 16);
}

__device__ __forceinline__ void gload_lds16(const void* g, void* l) {
    __builtin_amdgcn_global_load_lds(
        (const __attribute__((address_space(1))) unsigned int*)g,
        (__attribute__((address_space(3))) unsigned int*)l, 16, 0, 0);
}

// 1) affine[b][c] = latent . aw[:,c] + ab[c]; 128 blocks, split-K over l
__global__ void k_affine(const float* __restrict__ latent,
                         const float* __restrict__ aw,
                         const float* __restrict__ ab,
                         float* __restrict__ affine,
                         float* __restrict__ zbuf) {
    if (blockIdx.x == 0 && blockIdx.y == 0 && threadIdx.x < 16)
        zbuf[threadIdx.x] = 0.f;
    __shared__ float red[4][64];
    const int t  = threadIdx.x;
    const int cl = t & 63, lq = t >> 6;
    const int c  = blockIdx.x * 64 + cl;
    const int b  = blockIdx.y;
    float s = 0.f;
    #pragma unroll 4
    for (int l = lq * 128; l < lq * 128 + 128; ++l)
        s = fmaf(latent[b * LATn + l], aw[(size_t)l * Cn + c], s);
    red[lq][cl] = s;
    __syncthreads();
    if (t < 64)
        affine[b * Cn + blockIdx.x * 64 + t] =
            red[0][t] + red[1][t] + red[2][t] + red[3][t] + ab[blockIdx.x * 64 + t];
}

// 2a) Q[c][f] = sum_k kw[k][c][f]^2
__global__ void k_qsum(const float* __restrict__ kw, float* __restrict__ Q) {
    const int i = (blockIdx.x * 256 + threadIdx.x) * 4;
    const float4 a = *(const float4*)&kw[i];
    const float4 b = *(const float4*)&kw[Cn * Fn + i];
    const float4 c = *(const float4*)&kw[2 * Cn * Fn + i];
    float4 q;
    q.x = a.x * a.x + b.x * b.x + c.x * c.x;
    q.y = a.y * a.y + b.y * b.y + c.y * c.y;
    q.z = a.z * a.z + b.z * b.z + c.z * c.z;
    q.w = a.w * a.w + b.w * b.w + c.w * c.w;
    *(float4*)&Q[i] = q;
}

// 2b) demod[b][f] = rsqrt(sum_c affine^2 * Q[c][f] + 1e-8); 128 blocks, split-K
__global__ void k_demod2(const float* __restrict__ Q,
                         const float* __restrict__ affine,
                         float* __restrict__ demod) {
    __shared__ float red[4][64];
    const int t  = threadIdx.x;
    const int fl = t & 63, cq = t >> 6;
    const int f  = blockIdx.x * 64 + fl;
    const int b  = blockIdx.y;
    float s = 0.f;
    #pragma unroll 4
    for (int c = cq * 128; c < cq * 128 + 128; ++c) {
        const float a = affine[b * Cn + c];
        s = fmaf(a * a, Q[(size_t)c * Fn + f], s);
    }
    red[cq][fl] = s;
    __syncthreads();
    if (t < 64)
        demod[b * Fn + blockIdx.x * 64 + t] =
            rsqrtf(red[0][t] + red[1][t] + red[2][t] + red[3][t] + 1e-8f);
}

// 3) kt[k][f][c] = bf16(kw[k][c][f])
__global__ void k_tk(const float* __restrict__ kw, unsigned short* __restrict__ kt) {
    __shared__ float lds[32][65];
    const int t  = threadIdx.x;
    const int k  = blockIdx.z;
    const int c0 = blockIdx.x * 32;
    const int f0 = blockIdx.y * 64;
    #pragma unroll
    for (int i = 0; i < 8; ++i) {
        int e = t + 256 * i; int c = e >> 6; int f = e & 63;
        lds[c][f] = kw[((size_t)(k * Cn + c0 + c)) * Fn + f0 + f];
    }
    __syncthreads();
    #pragma unroll
    for (int i = 0; i < 8; ++i) {
        int e = t + 256 * i; int f = e >> 5; int c = e & 31;
        kt[((size_t)(k * Fn + f0 + f)) * Cn + c0 + c] = f2bf(lds[c][f]);
    }
}

// 4) xt[b][w][c] = bf16(content[b][c][w] * affine[b][c])
__global__ void k_tx(const float* __restrict__ content,
                     const float* __restrict__ affine,
                     unsigned short* __restrict__ xt) {
    __shared__ unsigned short lds[64][72];
    const int t  = threadIdx.x;
    const int b  = blockIdx.z;
    const int c0 = blockIdx.y * 64;
    const int w0 = blockIdx.x * 64;
    #pragma unroll
    for (int i = 0; i < 4; ++i) {
        int e = t + 256 * i;
        int c = e >> 4;
        int w4 = (e & 15) * 4;
        float4 v = *(const float4*)&content[((size_t)(b * Cn + c0 + c)) * Wn + w0 + w4];
        float a = affine[b * Cn + c0 + c];
        int wx = w4 ^ ((c >> 3) << 3);
        unsigned short p[4] = {f2bf(v.x * a), f2bf(v.y * a), f2bf(v.z * a), f2bf(v.w * a)};
        *(uint2*)&lds[c][wx] = *(const uint2*)p;
    }
    __syncthreads();
    #pragma unroll
    for (int i = 0; i < 2; ++i) {
        int e = t + 256 * i;
        int w  = e >> 3;
        int q  = e & 7;
        int c8 = q * 8;
        int wx = w ^ (q << 3);
        unsigned short tmp[8];
        #pragma unroll
        for (int j = 0; j < 8; ++j) tmp[j] = lds[c8 + j][wx];
        *(uint4*)&xt[((size_t)b * Wn + w0 + w) * Cn + c0 + c8] = *(uint4*)tmp;
    }
}

// 5) conv-GEMM: 256f x 256w, BK=32, 8 waves, 6 phases/K-tile (tap x m-half),
//    m201-style: reads+stage BEFORE barrier, lgkmcnt(0)+setprio MFMA cluster,
//    trailing barrier; vmcnt drain only once per tile (at p5).
#define BM 256
#define BN 256
#define BK 32
#define KBYTES (3 * BM * BK * 2)            // 49152 per buffer
#define BUFB   (KBYTES + BN * BK * 2)       // 65536 per buffer
#define SMEMB  (2 * BUFB + 2 * Cn * 2)      // 133120 total

extern __shared__ __align__(16) char smem[];

// 2 xt chunks per thread for K-slice c0s into buffer dst
#define ISSUE_XT(dst, c0s) { \
    _Pragma("unroll") for (int i_ = 0; i_ < 2; ++i_) { \
        const int Q_ = i_ * 512 + t; \
        const int r_ = Q_ >> 2; \
        const int j_ = (Q_ & 3) ^ ((r_ >> 1) & 3); \
        gload_lds16(&xt[((size_t)b * Wn + w0 + r_) * Cn + (c0s) + j_ * 8], \
                    (dst) + KBYTES + (size_t)Q_ * 16); } }

// 2 kt chunks (plane P) per thread
#define ISSUE_PLANE(dst, c0s, P) { \
    _Pragma("unroll") for (int i_ = 0; i_ < 2; ++i_) { \
        const int Q_ = i_ * 512 + t; \
        const int r_ = Q_ >> 2; \
        const int j_ = (Q_ & 3) ^ ((r_ >> 1) & 3); \
        gload_lds16(&kt[((size_t)((P) * Fn + f0 + r_)) * Cn + (c0s) + j_ * 8], \
                    (dst) + (size_t)((P) * 1024 + Q_) * 16); } }

// one phase = (tap K, m-half H): 16 MFMA. Reads + stage issued BEFORE barrier1
// so LDS latency hides under barrier skew; bv read at H==0, reused at H==1.
#define PHASE(K, H, PRE, POSTW) { \
    if ((H) == 0) { \
        _Pragma("unroll") for (int n_ = 0; n_ < 4; ++n_) { \
            const int rl_ = wn * 64 + n_ * 16 + l15 + (K) - 1; \
            const unsigned short* bp_ = xa + rl_ * 32 + (lhi ^ ((rl_ >> 1) & 3)) * 8; \
            if ((K) == 0 && n_ == 0 && rl_ < 0)   bp_ = halo + c0 + lhi * 8; \
            if ((K) == 2 && n_ == 3 && rl_ > 255) bp_ = halo + 512 + c0 + lhi * 8; \
            bv[n_] = *(const bf16x8*)bp_; } \
    } \
    bf16x8 af[4]; \
    _Pragma("unroll") for (int m_ = 0; m_ < 4; ++m_) { \
        const int r_ = wm * 128 + ((H) * 4 + m_) * 16 + l15; \
        af[m_] = *(const bf16x8*)(ka + ((K) * 256 + r_) * 32 + (lhi ^ ((r_ >> 1) & 3)) * 8); } \
    PRE; \
    asm volatile("s_barrier" ::: "memory"); \
    asm volatile("s_waitcnt lgkmcnt(0)" ::: "memory"); \
    __builtin_amdgcn_sched_barrier(0); \
    __builtin_amdgcn_s_setprio(1); \
    _Pragma("unroll") for (int n_ = 0; n_ < 4; ++n_) \
        _Pragma("unroll") for (int m_ = 0; m_ < 4; ++m_) \
            acc[(H) * 4 + m_][n_] = __builtin_amdgcn_mfma_f32_16x16x32_bf16( \
                af[m_], bv[n_], acc[(H) * 4 + m_][n_], 0, 0, 0); \
    __builtin_amdgcn_s_setprio(0); \
    POSTW; \
    asm volatile("s_barrier" ::: "memory"); }

__global__ __launch_bounds__(512, 1)
void k_conv(const unsigned short* __restrict__ kt,
            const unsigned short* __restrict__ xt,
            const float* __restrict__ demod,
            const float* __restrict__ kb,
            const float* __restrict__ zbuf,
            float* __restrict__ y) {
    const int t  = threadIdx.x;
    const int w0 = blockIdx.x * BN;
    const int f0 = blockIdx.y * BM;
    const int b  = blockIdx.z;

    const int wave = t >> 6;
    const int lane = t & 63;
    const int wm   = wave >> 2;
    const int wn   = wave & 3;
    const int l15  = lane & 15;
    const int lhi  = lane >> 4;

    unsigned short* halo = (unsigned short*)(smem + 2 * BUFB); // [2][512] c-natural

    f32x4 acc[8][4];
    #pragma unroll
    for (int m = 0; m < 8; ++m)
        #pragma unroll
        for (int n = 0; n < 4; ++n)
            #pragma unroll
            for (int r = 0; r < 4; ++r)
                acc[m][n][r] = 0.f;

    // prologue: halo rows + full tile 0, then one drain + barrier
    if (t < 128) {
        const int h  = t >> 6;
        const int wg = h ? (w0 + BN) : (w0 - 1);
        const unsigned short* src = ((unsigned)wg < (unsigned)Wn)
            ? &xt[((size_t)b * Wn + wg) * Cn + (t & 63) * 8]
            : (const unsigned short*)zbuf;
        gload_lds16(src, halo + (size_t)t * 8);
    }
    ISSUE_XT(smem, 0);
    ISSUE_PLANE(smem, 0, 0);
    ISSUE_PLANE(smem, 0, 1);
    ISSUE_PLANE(smem, 0, 2);
    asm volatile("s_waitcnt vmcnt(0)" ::: "memory");
    asm volatile("s_barrier" ::: "memory");

    int cur = 0;
    for (int cc = 0; cc < Cn / BK; ++cc) {
        const unsigned short* ka = (const unsigned short*)(smem + cur * BUFB);
        const unsigned short* xa = ka + 3 * BM * BK;
        char* nbuf = smem + (cur ^ 1) * BUFB;
        const int c0 = cc * BK;
        const int c1 = c0 + BK;
        const bool pf = cc < Cn / BK - 1;
        bf16x8 bv[4];
        // stage issues spread over p0..p3; vmcnt(0) drains them at p5 POSTW
        // (by then they've had ~5 phases to land -> effectively counted wait).
        PHASE(0, 0, if (pf) { ISSUE_XT(nbuf, c1); },      )
        PHASE(0, 1, if (pf) { ISSUE_PLANE(nbuf, c1, 0); },)
        PHASE(1, 0, if (pf) { ISSUE_PLANE(nbuf, c1, 1); },)
        PHASE(1, 1, if (pf) { ISSUE_PLANE(nbuf, c1, 2); },)
        PHASE(2, 0, ,                                     )
        PHASE(2, 1, , asm volatile("s_waitcnt vmcnt(0)" ::: "memory"))
        cur ^= 1;
    }

    // epilogue: demod * acc + kb, leaky_relu(0.2)
    #pragma unroll
    for (int m = 0; m < 8; ++m) {
        const int fb = f0 + wm * 128 + m * 16 + lhi * 4;
        const float4 dmv = *(const float4*)&demod[b * Fn + fb];
        const float4 kbv = *(const float4*)&kb[fb];
        const float dmf[4] = {dmv.x, dmv.y, dmv.z, dmv.w};
        const float kbf[4] = {kbv.x, kbv.y, kbv.z, kbv.w};
        #pragma unroll
        for (int n = 0; n < 4; ++n) {
            const int w = w0 + wn * 64 + n * 16 + l15;
            #pragma unroll
            for (int r = 0; r < 4; ++r) {
                float v = fmaf(acc[m][n][r], dmf[r], kbf[r]);
                v = (v >= 0.f) ? v : 0.2f * v;
                y[((size_t)(b * Fn + fb + r)) * Wn + w] = v;
            }
        }
    }
}

extern "C" void kernel_launch(void* const* d_in, const int* in_sizes, int n_in,
                              void* d_out, int out_size, void* d_ws, size_t ws_size,
                              hipStream_t stream) {
    const float* latent  = (const float*)d_in[0];
    const float* content = (const float*)d_in[1];
    const float* aw      = (const float*)d_in[2];
    const float* ab      = (const float*)d_in[3];
    const float* kw      = (const float*)d_in[4];
    const float* kb      = (const float*)d_in[5];
    float* y = (float*)d_out;

    char* ws = (char*)d_ws;
    float*          affine = (float*)(ws);                        // 32 KB
    float*          demod  = (float*)(ws + 32768);                // 32 KB
    float*          zbuf   = (float*)(ws + 65536);                // 64 B (zeroed)
    float*          Q      = (float*)(ws + 131072);               // 1 MB (aliases kt; consumed before k_tk)
    unsigned short* kt     = (unsigned short*)(ws + 131072);      // 1.5 MB
    unsigned short* xt     = (unsigned short*)(ws + 2u * 1024u * 1024u); // 64 MB
    if (ws_size < 2u * 1024u * 1024u + (size_t)Bn * Wn * Cn * 2u) return;

    hipFuncSetAttribute((const void*)k_conv,
                        hipFuncAttributeMaxDynamicSharedMemorySize, SMEMB);

    k_affine<<<dim3(Cn / 64, Bn),           256, 0, stream>>>(latent, aw, ab, affine, zbuf);
    k_qsum  <<<dim3(Cn * Fn / 1024),        256, 0, stream>>>(kw, Q);
    k_demod2<<<dim3(Fn / 64, Bn),           256, 0, stream>>>(Q, affine, demod);
    k_tk    <<<dim3(Cn / 32, Fn / 64, 3),   256, 0, stream>>>(kw, kt);
    k_tx    <<<dim3(Wn / 64, Cn / 64, Bn),  256, 0, stream>>>(content, affine, xt);
    k_conv  <<<dim3(Wn / BN, Fn / BM, Bn),  512, SMEMB, stream>>>(kt, xt, demod, kb, zbuf, y);
}

// Round 8
// 165.913 us; speedup vs baseline: 1.0276x; 1.0276x over previous
//
#include <hip/hip_runtime.h>
#include <hip/hip_bf16.h>

#define Bn   16
#define LATn 512
#define Cn   512
#define Wn   4096
#define Fn   512

using bf16x8 = __attribute__((ext_vector_type(8))) short;
using f32x16 = __attribute__((ext_vector_type(16))) float;

__device__ __forceinline__ unsigned short f2bf(float x) {
    union { float f; unsigned int u; } v; v.f = x;
    unsigned int r = v.u + 0x7fffu + ((v.u >> 16) & 1u);
    return (unsigned short)(r >> 16);
}

__device__ __forceinline__ void gload_lds16(const void* g, void* l) {
    __builtin_amdgcn_global_load_lds(
        (const __attribute__((address_space(1))) unsigned int*)g,
        (__attribute__((address_space(3))) unsigned int*)l, 16, 0, 0);
}

// L1) affine[b][c] = latent . aw[:,c] + ab[c]; 128 blocks, split-K over l
__global__ void k_affine(const float* __restrict__ latent,
                         const float* __restrict__ aw,
                         const float* __restrict__ ab,
                         float* __restrict__ affine) {
    __shared__ float red[4][64];
    const int t  = threadIdx.x;
    const int cl = t & 63, lq = t >> 6;
    const int c  = blockIdx.x * 64 + cl;
    const int b  = blockIdx.y;
    float s = 0.f;
    #pragma unroll 4
    for (int l = lq * 128; l < lq * 128 + 128; ++l)
        s = fmaf(latent[b * LATn + l], aw[(size_t)l * Cn + c], s);
    red[lq][cl] = s;
    __syncthreads();
    if (t < 64)
        affine[b * Cn + blockIdx.x * 64 + t] =
            red[0][t] + red[1][t] + red[2][t] + red[3][t] + ab[blockIdx.x * 64 + t];
}

// L2) fused roles: demod (128 blk) | kt transpose (384 blk) | xt modulate-transpose (8192 blk)
__global__ __launch_bounds__(256)
void k_mid(const float* __restrict__ kw,
           const float* __restrict__ affine,
           const float* __restrict__ content,
           float* __restrict__ demod,
           unsigned short* __restrict__ kt,
           unsigned short* __restrict__ xt) {
    __shared__ __align__(16) char shraw[9216];
    const int t   = threadIdx.x;
    const int bid = blockIdx.x;

    if (bid < 128) {
        // demod[b][f] = rsqrt(sum_{k,c} kw[k][c][f]^2 * affine[b][c]^2 + 1e-8)
        float (*red)[64] = (float(*)[64])shraw;
        const int fl = t & 63, cq = t >> 6;
        const int f  = (bid & 7) * 64 + fl;
        const int b  = bid >> 3;
        float s = 0.f;
        for (int c = cq * 128; c < cq * 128 + 128; ++c) {
            const float a  = affine[b * Cn + c];
            const float k0 = kw[((size_t)(0 * Cn + c)) * Fn + f];
            const float k1 = kw[((size_t)(1 * Cn + c)) * Fn + f];
            const float k2 = kw[((size_t)(2 * Cn + c)) * Fn + f];
            s = fmaf(k0 * k0 + k1 * k1 + k2 * k2, a * a, s);
        }
        red[cq][fl] = s;
        __syncthreads();
        if (t < 64)
            demod[b * Fn + (bid & 7) * 64 + t] =
                rsqrtf(red[0][t] + red[1][t] + red[2][t] + red[3][t] + 1e-8f);
    } else if (bid < 512) {
        // kt[k][f][c] = bf16(kw[k][c][f])
        float (*lds)[65] = (float(*)[65])shraw;
        const int e  = bid - 128;
        const int k  = e / 128;
        const int e2 = e % 128;
        const int c0 = (e2 & 15) * 32;
        const int f0 = (e2 >> 4) * 64;
        #pragma unroll
        for (int i = 0; i < 8; ++i) {
            int q = t + 256 * i; int c = q >> 6; int f = q & 63;
            lds[c][f] = kw[((size_t)(k * Cn + c0 + c)) * Fn + f0 + f];
        }
        __syncthreads();
        #pragma unroll
        for (int i = 0; i < 8; ++i) {
            int q = t + 256 * i; int f = q >> 5; int c = q & 31;
            kt[((size_t)(k * Fn + f0 + f)) * Cn + c0 + c] = f2bf(lds[c][f]);
        }
    } else {
        // xt[b][w][c] = bf16(content[b][c][w] * affine[b][c]), swizzled LDS transpose
        unsigned short (*lds)[72] = (unsigned short(*)[72])shraw;
        const int e  = bid - 512;
        const int w0 = (e & 63) * 64;
        const int c0 = ((e >> 6) & 7) * 64;
        const int b  = e >> 9;
        #pragma unroll
        for (int i = 0; i < 4; ++i) {
            int q = t + 256 * i;
            int c = q >> 4;
            int w4 = (q & 15) * 4;
            float4 v = *(const float4*)&content[((size_t)(b * Cn + c0 + c)) * Wn + w0 + w4];
            float a = affine[b * Cn + c0 + c];
            int wx = w4 ^ ((c >> 3) << 3);
            unsigned short p[4] = {f2bf(v.x * a), f2bf(v.y * a), f2bf(v.z * a), f2bf(v.w * a)};
            *(uint2*)&lds[c][wx] = *(const uint2*)p;
        }
        __syncthreads();
        #pragma unroll
        for (int i = 0; i < 2; ++i) {
            int q  = t + 256 * i;
            int w  = q >> 3;
            int qq = q & 7;
            int c8 = qq * 8;
            int wx = w ^ (qq << 3);
            unsigned short tmp[8];
            #pragma unroll
            for (int j = 0; j < 8; ++j) tmp[j] = lds[c8 + j][wx];
            *(uint4*)&xt[((size_t)b * Wn + w0 + w) * Cn + c0 + c8] = *(uint4*)tmp;
        }
    }
}

// L3) conv-GEMM: 256f x 256w, BK=32, 8 waves, 32x32x16 MFMA, 3-phase counted vmcnt
#define BM 256
#define BN 256
#define BK 32
#define ABYTES (3 * BM * BK * 2)        // 49152
#define XROWS  258
#define XBYTES (XROWS * BK * 2)         // 16512
#define BUFB   (ABYTES + XBYTES)        // 65664
#define ZOFF   (2 * BUFB)               // 131328
#define SMEMB  (ZOFF + 64)              // 131392

extern __shared__ __align__(16) char smem[];

// X stage: 258 rows (w0-1 .. w0+256, clamped), 1032 chunks: 2/thread + 1 lane0/wave
#define ISSUE_XT(dst, c0s) { \
    _Pragma("unroll") for (int i_ = 0; i_ < 2; ++i_) { \
        const int Q_ = i_ * 512 + t; \
        const int r_ = Q_ >> 2; \
        const int j_ = (Q_ & 3) ^ ((r_ >> 1) & 3); \
        int wg_ = w0 - 1 + r_; wg_ = wg_ < 0 ? 0 : wg_; \
        gload_lds16(&xt[((size_t)b * Wn + wg_) * Cn + (c0s) + j_ * 8], \
                    (dst) + ABYTES + (size_t)Q_ * 16); } \
    { const int Q_ = 1024 + wave; \
      const int r_ = Q_ >> 2; \
      const int j_ = (Q_ & 3) ^ ((r_ >> 1) & 3); \
      int wg_ = w0 - 1 + r_; wg_ = wg_ > Wn - 1 ? Wn - 1 : wg_; \
      if (lane == 0) \
          gload_lds16(&xt[((size_t)b * Wn + wg_) * Cn + (c0s) + j_ * 8], \
                      (dst) + ABYTES + (size_t)Q_ * 16); } }

#define ISSUE_PLANE(dst, c0s, P) { \
    _Pragma("unroll") for (int i_ = 0; i_ < 2; ++i_) { \
        const int Q_ = i_ * 512 + t; \
        const int r_ = (Q_ >> 2) & 255; \
        const int j_ = (Q_ & 3) ^ ((r_ >> 1) & 3); \
        gload_lds16(&kt[((size_t)((P) * Fn + f0 + r_)) * Cn + (c0s) + j_ * 8], \
                    (dst) + (size_t)((P) * 1024 + Q_) * 16); } }

// one phase = tap K: vmcnt(VM) -> barrier -> frag reads -> prefetch issue ->
// lgkmcnt(0)+sched_barrier -> setprio-wrapped 16 MFMA (32x32x16)
#define PHASE(K, VM, ...) { \
    asm volatile("s_waitcnt vmcnt(" #VM ")" ::: "memory"); \
    asm volatile("s_barrier" ::: "memory"); \
    bf16x8 af[8]; bf16x8 bv[4]; \
    _Pragma("unroll") for (int mt_ = 0; mt_ < 4; ++mt_) \
    _Pragma("unroll") for (int ks_ = 0; ks_ < 2; ++ks_) { \
        const int r_ = wm * 128 + mt_ * 32 + l31; \
        af[mt_ * 2 + ks_] = *(const bf16x8*)(ka + ((K) * 256 + r_) * 32 \
            + ((ks_ * 2 + lhi2) ^ ((r_ >> 1) & 3)) * 8); } \
    _Pragma("unroll") for (int nt_ = 0; nt_ < 2; ++nt_) \
    _Pragma("unroll") for (int ks_ = 0; ks_ < 2; ++ks_) { \
        const int gw_ = w0 + wn * 64 + nt_ * 32 + l31 + (K) - 1; \
        const int rw_ = wn * 64 + nt_ * 32 + l31 + (K);          /* LDS row = rl+1 */ \
        const unsigned short* bp_ = xa + rw_ * 32 + ((ks_ * 2 + lhi2) ^ ((rw_ >> 1) & 3)) * 8; \
        if ((K) == 0 && nt_ == 0) bp_ = (gw_ < 0)      ? zl : bp_; \
        if ((K) == 2 && nt_ == 1) bp_ = (gw_ > Wn - 1) ? zl : bp_; \
        bv[nt_ * 2 + ks_] = *(const bf16x8*)bp_; } \
    __VA_ARGS__; \
    asm volatile("s_waitcnt lgkmcnt(0)" ::: "memory"); \
    __builtin_amdgcn_sched_barrier(0); \
    __builtin_amdgcn_s_setprio(1); \
    _Pragma("unroll") for (int ks_ = 0; ks_ < 2; ++ks_) \
    _Pragma("unroll") for (int nt_ = 0; nt_ < 2; ++nt_) \
    _Pragma("unroll") for (int mt_ = 0; mt_ < 4; ++mt_) \
        acc[mt_][nt_] = __builtin_amdgcn_mfma_f32_32x32x16_bf16( \
            af[mt_ * 2 + ks_], bv[nt_ * 2 + ks_], acc[mt_][nt_], 0, 0, 0); \
    __builtin_amdgcn_s_setprio(0); }

__global__ __launch_bounds__(512, 1)
void k_conv(const unsigned short* __restrict__ kt,
            const unsigned short* __restrict__ xt,
            const float* __restrict__ demod,
            const float* __restrict__ kb,
            float* __restrict__ y) {
    const int t  = threadIdx.x;
    const int w0 = blockIdx.x * BN;
    const int f0 = blockIdx.y * BM;
    const int b  = blockIdx.z;

    const int wave = t >> 6;
    const int lane = t & 63;
    const int wm   = wave >> 2;   // f 128-half
    const int wn   = wave & 3;    // w 64-quarter
    const int l31  = lane & 31;
    const int lhi2 = lane >> 5;

    const unsigned short* zl = (const unsigned short*)(smem + ZOFF);

    f32x16 acc[4][2];
    #pragma unroll
    for (int m = 0; m < 4; ++m)
        #pragma unroll
        for (int n = 0; n < 2; ++n)
            #pragma unroll
            for (int r = 0; r < 16; ++r)
                acc[m][n][r] = 0.f;

    // prologue: zero region + tile-0 issues (9 loads/wave, uniform)
    if (t < 4) { uint4 z = {0u, 0u, 0u, 0u}; *(uint4*)(smem + ZOFF + t * 16) = z; }
    ISSUE_XT(smem, 0);
    ISSUE_PLANE(smem, 0, 0);
    ISSUE_PLANE(smem, 0, 1);
    ISSUE_PLANE(smem, 0, 2);
    asm volatile("s_waitcnt lgkmcnt(0)" ::: "memory");   // zero-region ds_write drained

    int cur = 0;
    // loads per tile per wave: X=3, P0=2, P1=2, P2=2 (9). Steady-state waits:
    // p0 needs X,P0 -> allow P1+P2=4; p1 needs P1 -> allow 7; p2 needs P2 -> allow 7.
    for (int cc = 0; cc < Cn / BK - 1; ++cc) {
        const unsigned short* ka = (const unsigned short*)(smem + cur * BUFB);
        const unsigned short* xa = ka + 3 * BM * BK;
        char* nbuf = smem + (cur ^ 1) * BUFB;
        const int c1 = (cc + 1) * BK;
        PHASE(0, 4, ISSUE_XT(nbuf, c1); ISSUE_PLANE(nbuf, c1, 0);)
        PHASE(1, 7, ISSUE_PLANE(nbuf, c1, 1);)
        PHASE(2, 7, ISSUE_PLANE(nbuf, c1, 2);)
        cur ^= 1;
    }
    {   // peeled last tile: no prefetch, tighter waits
        const unsigned short* ka = (const unsigned short*)(smem + cur * BUFB);
        const unsigned short* xa = ka + 3 * BM * BK;
        PHASE(0, 4, )
        PHASE(1, 2, )
        PHASE(2, 0, )
    }

    // epilogue: demod * acc + kb, leaky_relu(0.2)
    // C/D 32x32: col = lane&31 (w), row = (reg&3) + 8*(reg>>2) + 4*(lane>>5) (f)
    #pragma unroll
    for (int mt = 0; mt < 4; ++mt) {
        #pragma unroll
        for (int g = 0; g < 4; ++g) {
            const int fb = f0 + wm * 128 + mt * 32 + g * 8 + lhi2 * 4;
            const float4 dm = *(const float4*)&demod[b * Fn + fb];
            const float4 kv = *(const float4*)&kb[fb];
            const float dmf[4] = {dm.x, dm.y, dm.z, dm.w};
            const float kbf[4] = {kv.x, kv.y, kv.z, kv.w};
            #pragma unroll
            for (int nt = 0; nt < 2; ++nt) {
                const int w = w0 + wn * 64 + nt * 32 + l31;
                #pragma unroll
                for (int r2 = 0; r2 < 4; ++r2) {
                    float v = fmaf(acc[mt][nt][g * 4 + r2], dmf[r2], kbf[r2]);
                    v = (v >= 0.f) ? v : 0.2f * v;
                    y[((size_t)(b * Fn + fb + r2)) * Wn + w] = v;
                }
            }
        }
    }
}

extern "C" void kernel_launch(void* const* d_in, const int* in_sizes, int n_in,
                              void* d_out, int out_size, void* d_ws, size_t ws_size,
                              hipStream_t stream) {
    const float* latent  = (const float*)d_in[0];
    const float* content = (const float*)d_in[1];
    const float* aw      = (const float*)d_in[2];
    const float* ab      = (const float*)d_in[3];
    const float* kw      = (const float*)d_in[4];
    const float* kb      = (const float*)d_in[5];
    float* y = (float*)d_out;

    char* ws = (char*)d_ws;
    float*          affine = (float*)(ws);                        // 32 KB
    float*          demod  = (float*)(ws + 32768);                // 32 KB
    unsigned short* kt     = (unsigned short*)(ws + 131072);      // 1.5 MB
    unsigned short* xt     = (unsigned short*)(ws + 2u * 1024u * 1024u); // 64 MB
    if (ws_size < 2u * 1024u * 1024u + (size_t)Bn * Wn * Cn * 2u) return;

    hipFuncSetAttribute((const void*)k_conv,
                        hipFuncAttributeMaxDynamicSharedMemorySize, SMEMB);

    k_affine<<<dim3(Cn / 64, Bn),          256, 0, stream>>>(latent, aw, ab, affine);
    k_mid   <<<dim3(128 + 384 + Wn / 64 * Cn / 64 * Bn), 256, 0, stream>>>(
            kw, affine, content, demod, kt, xt);
    k_conv  <<<dim3(Wn / BN, Fn / BM, Bn), 512, SMEMB, stream>>>(kt, xt, demod, kb, y);
}

// Round 9
// 154.409 us; speedup vs baseline: 1.1042x; 1.0745x over previous
//
#include <hip/hip_runtime.h>
#include <hip/hip_bf16.h>

#define Bn   16
#define LATn 512
#define Cn   512
#define Wn   4096
#define Fn   512

using bf16x8 = __attribute__((ext_vector_type(8))) short;
using f32x4  = __attribute__((ext_vector_type(4))) float;

__device__ __forceinline__ unsigned short f2bf(float x) {
    union { float f; unsigned int u; } v; v.f = x;
    unsigned int r = v.u + 0x7fffu + ((v.u >> 16) & 1u);
    return (unsigned short)(r >> 16);
}

__device__ __forceinline__ void gload_lds16(const void* g, void* l) {
    __builtin_amdgcn_global_load_lds(
        (const __attribute__((address_space(1))) unsigned int*)g,
        (__attribute__((address_space(3))) unsigned int*)l, 16, 0, 0);
}

// L1) affine[b][c] = latent . aw[:,c] + ab[c]; 128 blocks, split-K over l (+ zero zbuf)
__global__ void k_affine(const float* __restrict__ latent,
                         const float* __restrict__ aw,
                         const float* __restrict__ ab,
                         float* __restrict__ affine,
                         float* __restrict__ zbuf) {
    if (blockIdx.x == 0 && blockIdx.y == 0 && threadIdx.x < 16)
        zbuf[threadIdx.x] = 0.f;
    __shared__ float red[4][64];
    const int t  = threadIdx.x;
    const int cl = t & 63, lq = t >> 6;
    const int c  = blockIdx.x * 64 + cl;
    const int b  = blockIdx.y;
    float s = 0.f;
    #pragma unroll 4
    for (int l = lq * 128; l < lq * 128 + 128; ++l)
        s = fmaf(latent[b * LATn + l], aw[(size_t)l * Cn + c], s);
    red[lq][cl] = s;
    __syncthreads();
    if (t < 64)
        affine[b * Cn + blockIdx.x * 64 + t] =
            red[0][t] + red[1][t] + red[2][t] + red[3][t] + ab[blockIdx.x * 64 + t];
}

// L2) fused roles: demod (128 blk) | kt transpose (384 blk) | xt modulate-transpose (8192 blk)
__global__ __launch_bounds__(256)
void k_mid(const float* __restrict__ kw,
           const float* __restrict__ affine,
           const float* __restrict__ content,
           float* __restrict__ demod,
           unsigned short* __restrict__ kt,
           unsigned short* __restrict__ xt) {
    __shared__ __align__(16) char shraw[9216];
    const int t   = threadIdx.x;
    const int bid = blockIdx.x;

    if (bid < 128) {
        // demod[b][f] = rsqrt(sum_{k,c} kw[k][c][f]^2 * affine[b][c]^2 + 1e-8)
        float (*red)[64] = (float(*)[64])shraw;
        const int fl = t & 63, cq = t >> 6;
        const int f  = (bid & 7) * 64 + fl;
        const int b  = bid >> 3;
        float s = 0.f;
        for (int c = cq * 128; c < cq * 128 + 128; ++c) {
            const float a  = affine[b * Cn + c];
            const float k0 = kw[((size_t)(0 * Cn + c)) * Fn + f];
            const float k1 = kw[((size_t)(1 * Cn + c)) * Fn + f];
            const float k2 = kw[((size_t)(2 * Cn + c)) * Fn + f];
            s = fmaf(k0 * k0 + k1 * k1 + k2 * k2, a * a, s);
        }
        red[cq][fl] = s;
        __syncthreads();
        if (t < 64)
            demod[b * Fn + (bid & 7) * 64 + t] =
                rsqrtf(red[0][t] + red[1][t] + red[2][t] + red[3][t] + 1e-8f);
    } else if (bid < 512) {
        // kt[k][f][c] = bf16(kw[k][c][f])
        float (*lds)[65] = (float(*)[65])shraw;
        const int e  = bid - 128;
        const int k  = e / 128;
        const int e2 = e % 128;
        const int c0 = (e2 & 15) * 32;
        const int f0 = (e2 >> 4) * 64;
        #pragma unroll
        for (int i = 0; i < 8; ++i) {
            int q = t + 256 * i; int c = q >> 6; int f = q & 63;
            lds[c][f] = kw[((size_t)(k * Cn + c0 + c)) * Fn + f0 + f];
        }
        __syncthreads();
        #pragma unroll
        for (int i = 0; i < 8; ++i) {
            int q = t + 256 * i; int f = q >> 5; int c = q & 31;
            kt[((size_t)(k * Fn + f0 + f)) * Cn + c0 + c] = f2bf(lds[c][f]);
        }
    } else {
        // xt[b][w][c] = bf16(content[b][c][w] * affine[b][c]), swizzled LDS transpose
        unsigned short (*lds)[72] = (unsigned short(*)[72])shraw;
        const int e  = bid - 512;
        const int w0 = (e & 63) * 64;
        const int c0 = ((e >> 6) & 7) * 64;
        const int b  = e >> 9;
        #pragma unroll
        for (int i = 0; i < 4; ++i) {
            int q = t + 256 * i;
            int c = q >> 4;
            int w4 = (q & 15) * 4;
            float4 v = *(const float4*)&content[((size_t)(b * Cn + c0 + c)) * Wn + w0 + w4];
            float a = affine[b * Cn + c0 + c];
            int wx = w4 ^ ((c >> 3) << 3);
            unsigned short p[4] = {f2bf(v.x * a), f2bf(v.y * a), f2bf(v.z * a), f2bf(v.w * a)};
            *(uint2*)&lds[c][wx] = *(const uint2*)p;
        }
        __syncthreads();
        #pragma unroll
        for (int i = 0; i < 2; ++i) {
            int q  = t + 256 * i;
            int w  = q >> 3;
            int qq = q & 7;
            int c8 = qq * 8;
            int wx = w ^ (qq << 3);
            unsigned short tmp[8];
            #pragma unroll
            for (int j = 0; j < 8; ++j) tmp[j] = lds[c8 + j][wx];
            *(uint4*)&xt[((size_t)b * Wn + w0 + w) * Cn + c0 + c8] = *(uint4*)tmp;
        }
    }
}

// L3) conv-GEMM: 256f x 256w, BK=32, 8 waves, 16x16x32 MFMA, 3 phases/K-tile,
//    counted vmcnt (R5 structure, benched 97.3us) + race-fixed peeled last tile
#define BM 256
#define BN 256
#define BK 32
#define KBYTES (3 * BM * BK * 2)            // 49152 per buffer
#define BUFB   (KBYTES + BN * BK * 2)       // 65536 per buffer
#define SMEMB  (2 * BUFB + 2 * Cn * 2)      // 133120 total

extern __shared__ __align__(16) char smem[];

// 2 xt chunks per thread: rows r=0..255 hold w = w0 + r
#define ISSUE_XT(dst, c0s) { \
    _Pragma("unroll") for (int i_ = 0; i_ < 2; ++i_) { \
        const int Q_ = i_ * 512 + t; \
        const int r_ = Q_ >> 2; \
        const int j_ = (Q_ & 3) ^ ((r_ >> 1) & 3); \
        gload_lds16(&xt[((size_t)b * Wn + w0 + r_) * Cn + (c0s) + j_ * 8], \
                    (dst) + KBYTES + (size_t)Q_ * 16); } }

// 2 kt chunks (plane P) per thread
#define ISSUE_PLANE(dst, c0s, P) { \
    _Pragma("unroll") for (int i_ = 0; i_ < 2; ++i_) { \
        const int Q_ = i_ * 512 + t; \
        const int r_ = (Q_ >> 2) & 255; \
        const int j_ = (Q_ & 3) ^ ((r_ >> 1) & 3); \
        gload_lds16(&kt[((size_t)((P) * Fn + f0 + r_)) * Cn + (c0s) + j_ * 8], \
                    (dst) + (size_t)((P) * 1024 + Q_) * 16); } }

// one phase = k-tap K: vmcnt(VM) -> barrier -> frag reads -> prefetch issue ->
// lgkmcnt(0)+sched_barrier -> setprio-wrapped 32 MFMA
#define PHASE(K, VM, ...) { \
    asm volatile("s_waitcnt vmcnt(" #VM ")" ::: "memory"); \
    asm volatile("s_barrier" ::: "memory"); \
    bf16x8 af[8]; bf16x8 bv[4]; \
    _Pragma("unroll") for (int m_ = 0; m_ < 8; ++m_) { \
        const int r_ = wm * 128 + m_ * 16 + l15; \
        af[m_] = *(const bf16x8*)(ka + ((K) * 256 + r_) * 32 + (lhi ^ ((r_ >> 1) & 3)) * 8); } \
    _Pragma("unroll") for (int n_ = 0; n_ < 4; ++n_) { \
        const int rl_ = wn * 64 + n_ * 16 + l15 + (K) - 1; \
        const unsigned short* bp_ = xa + rl_ * 32 + (lhi ^ ((rl_ >> 1) & 3)) * 8; \
        if ((K) == 0 && n_ == 0 && rl_ < 0)   bp_ = halo + c0 + lhi * 8; \
        if ((K) == 2 && n_ == 3 && rl_ > 255) bp_ = halo + 512 + c0 + lhi * 8; \
        bv[n_] = *(const bf16x8*)bp_; } \
    __VA_ARGS__; \
    asm volatile("s_waitcnt lgkmcnt(0)" ::: "memory"); \
    __builtin_amdgcn_sched_barrier(0); \
    __builtin_amdgcn_s_setprio(1); \
    _Pragma("unroll") for (int n_ = 0; n_ < 4; ++n_) \
        _Pragma("unroll") for (int m_ = 0; m_ < 8; ++m_) \
            acc[m_][n_] = __builtin_amdgcn_mfma_f32_16x16x32_bf16(af[m_], bv[n_], acc[m_][n_], 0, 0, 0); \
    __builtin_amdgcn_s_setprio(0); }

__global__ __launch_bounds__(512, 1)
void k_conv(const unsigned short* __restrict__ kt,
            const unsigned short* __restrict__ xt,
            const float* __restrict__ demod,
            const float* __restrict__ kb,
            const float* __restrict__ zbuf,
            float* __restrict__ y) {
    const int t  = threadIdx.x;
    const int w0 = blockIdx.x * BN;
    const int f0 = blockIdx.y * BM;
    const int b  = blockIdx.z;

    const int wave = t >> 6;
    const int lane = t & 63;
    const int wm   = wave >> 2;
    const int wn   = wave & 3;
    const int l15  = lane & 15;
    const int lhi  = lane >> 4;

    unsigned short* halo = (unsigned short*)(smem + 2 * BUFB); // [2][512] c-natural

    f32x4 acc[8][4];
    #pragma unroll
    for (int m = 0; m < 8; ++m)
        #pragma unroll
        for (int n = 0; n < 4; ++n)
            #pragma unroll
            for (int r = 0; r < 4; ++r)
                acc[m][n][r] = 0.f;

    // prologue: halo rows (w0-1, w0+BN across all 512 c) + tile-0 issues.
    // First PHASE's vmcnt(4) drains halo + X + P0 before any read.
    if (t < 128) {
        const int h  = t >> 6;
        const int wg = h ? (w0 + BN) : (w0 - 1);
        const unsigned short* src = ((unsigned)wg < (unsigned)Wn)
            ? &xt[((size_t)b * Wn + wg) * Cn + (t & 63) * 8]
            : (const unsigned short*)zbuf;
        gload_lds16(src, halo + (size_t)t * 8);
    }
    ISSUE_XT(smem, 0);
    ISSUE_PLANE(smem, 0, 0);
    ISSUE_PLANE(smem, 0, 1);
    ISSUE_PLANE(smem, 0, 2);

    int cur = 0;
    for (int cc = 0; cc < Cn / BK - 1; ++cc) {
        const unsigned short* ka = (const unsigned short*)(smem + cur * BUFB);
        const unsigned short* xa = ka + 3 * BM * BK;
        char* nbuf = smem + (cur ^ 1) * BUFB;
        const int c0 = cc * BK;
        const int c1 = c0 + BK;
        // steady-state outstanding at each vmcnt: p0 drains {X,P0} (oldest, keep 4);
        // p1 drains {P1} (keep 6); p2 drains {P2} (keep 6).
        PHASE(0, 4, ISSUE_XT(nbuf, c1); ISSUE_PLANE(nbuf, c1, 0);)
        PHASE(1, 6, ISSUE_PLANE(nbuf, c1, 1);)
        PHASE(2, 6, ISSUE_PLANE(nbuf, c1, 2);)
        cur ^= 1;
    }
    {   // peeled last tile: no prefetch; tight waits guarantee P1/P2 landed
        const unsigned short* ka = (const unsigned short*)(smem + cur * BUFB);
        const unsigned short* xa = ka + 3 * BM * BK;
        const int c0 = Cn - BK;
        PHASE(0, 4, )
        PHASE(1, 2, )
        PHASE(2, 0, )
    }

    // epilogue: demod * acc + kb, leaky_relu(0.2)
    #pragma unroll
    for (int m = 0; m < 8; ++m) {
        const int fb = f0 + wm * 128 + m * 16 + lhi * 4;
        const float4 dmv = *(const float4*)&demod[b * Fn + fb];
        const float4 kbv = *(const float4*)&kb[fb];
        const float dmf[4] = {dmv.x, dmv.y, dmv.z, dmv.w};
        const float kbf[4] = {kbv.x, kbv.y, kbv.z, kbv.w};
        #pragma unroll
        for (int n = 0; n < 4; ++n) {
            const int w = w0 + wn * 64 + n * 16 + l15;
            #pragma unroll
            for (int r = 0; r < 4; ++r) {
                float v = fmaf(acc[m][n][r], dmf[r], kbf[r]);
                v = (v >= 0.f) ? v : 0.2f * v;
                y[((size_t)(b * Fn + fb + r)) * Wn + w] = v;
            }
        }
    }
}

extern "C" void kernel_launch(void* const* d_in, const int* in_sizes, int n_in,
                              void* d_out, int out_size, void* d_ws, size_t ws_size,
                              hipStream_t stream) {
    const float* latent  = (const float*)d_in[0];
    const float* content = (const float*)d_in[1];
    const float* aw      = (const float*)d_in[2];
    const float* ab      = (const float*)d_in[3];
    const float* kw      = (const float*)d_in[4];
    const float* kb      = (const float*)d_in[5];
    float* y = (float*)d_out;

    char* ws = (char*)d_ws;
    float*          affine = (float*)(ws);                        // 32 KB
    float*          demod  = (float*)(ws + 32768);                // 32 KB
    float*          zbuf   = (float*)(ws + 65536);                // 64 B (zeroed by k_affine)
    unsigned short* kt     = (unsigned short*)(ws + 131072);      // 1.5 MB
    unsigned short* xt     = (unsigned short*)(ws + 2u * 1024u * 1024u); // 64 MB
    if (ws_size < 2u * 1024u * 1024u + (size_t)Bn * Wn * Cn * 2u) return;

    hipFuncSetAttribute((const void*)k_conv,
                        hipFuncAttributeMaxDynamicSharedMemorySize, SMEMB);

    k_affine<<<dim3(Cn / 64, Bn),                        256, 0, stream>>>(latent, aw, ab, affine, zbuf);
    k_mid   <<<dim3(128 + 384 + Wn / 64 * Cn / 64 * Bn), 256, 0, stream>>>(kw, affine, content, demod, kt, xt);
    k_conv  <<<dim3(Wn / BN, Fn / BM, Bn),               512, SMEMB, stream>>>(kt, xt, demod, kb, zbuf, y);
}